// Round 1
// baseline (3560.541 us; speedup 1.0000x reference)
//
#include <hip/hip_runtime.h>
#include <math.h>

#define T_TOK 4096
#define H_DIM 1024
#define I_DIM 768
#define E_NUM 32
#define G_NUM 8
#define TOPKG 4
#define TOPK 4
#define ASSIGN (T_TOK * TOPK) /* 16384 */

#define TM 64
#define TN 64
#define KC 16

// ---------------- zero out + counts ----------------
__global__ void zero_kernel(float* __restrict__ out, int n4, int* __restrict__ counts) {
    int gid = blockIdx.x * blockDim.x + threadIdx.x;
    if (gid < n4) ((float4*)out)[gid] = make_float4(0.f, 0.f, 0.f, 0.f);
    if (gid < E_NUM) counts[gid] = 0;
}

// ---------------- router: sigmoid + bias, group-limited top-k ----------------
__global__ __launch_bounds__(128) void router_kernel(
    const float* __restrict__ x, const float* __restrict__ rw,
    const float* __restrict__ bias, int* __restrict__ topk_idx,
    float* __restrict__ topk_w)
{
    int t = blockIdx.x;
    int tid = threadIdx.x;
    __shared__ float part[128];
    __shared__ float s_arr[E_NUM];
    __shared__ float sc_arr[E_NUM];

    int e = tid >> 2, sub = tid & 3;
    const float* xr = x + (size_t)t * H_DIM;
    const float* wr = rw + (size_t)e * H_DIM;
    float acc = 0.f;
    for (int h = sub * 4; h < H_DIM; h += 16) {
        float4 xv = *(const float4*)(xr + h);
        float4 wv = *(const float4*)(wr + h);
        acc += xv.x * wv.x + xv.y * wv.y + xv.z * wv.z + xv.w * wv.w;
    }
    part[tid] = acc;
    __syncthreads();
    if (tid < E_NUM) {
        float l = part[tid * 4 + 0] + part[tid * 4 + 1] + part[tid * 4 + 2] + part[tid * 4 + 3];
        float s = 1.f / (1.f + expf(-l));
        s_arr[tid] = s;
        sc_arr[tid] = s + bias[tid];
    }
    __syncthreads();
    if (tid == 0) {
        // group scores = top1+top2 within each group of 4
        float gs[G_NUM];
        for (int g = 0; g < G_NUM; ++g) {
            float m1 = -1e30f, m2 = -1e30f;
            for (int j = 0; j < 4; ++j) {
                float v = sc_arr[g * 4 + j];
                if (v > m1) { m2 = m1; m1 = v; }
                else if (v > m2) { m2 = v; }
            }
            gs[g] = m1 + m2;
        }
        // top-4 groups (tie -> lower index, via strict > ascending scan)
        bool gsel[G_NUM];
        for (int g = 0; g < G_NUM; ++g) gsel[g] = false;
        for (int it = 0; it < TOPKG; ++it) {
            float best = -1e30f; int bi = 0;
            for (int g = 0; g < G_NUM; ++g)
                if (!gsel[g] && gs[g] > best) { best = gs[g]; bi = g; }
            gsel[bi] = true;
        }
        // masked scores, top-4 experts
        float sfc[E_NUM];
        for (int i2 = 0; i2 < E_NUM; ++i2) sfc[i2] = gsel[i2 >> 2] ? sc_arr[i2] : 0.0f;
        bool taken[E_NUM];
        for (int i2 = 0; i2 < E_NUM; ++i2) taken[i2] = false;
        int idx[TOPK]; float w[TOPK]; float wsum = 0.f;
        for (int k = 0; k < TOPK; ++k) {
            float best = -1e30f; int bi = 0;
            for (int i2 = 0; i2 < E_NUM; ++i2)
                if (!taken[i2] && sfc[i2] > best) { best = sfc[i2]; bi = i2; }
            taken[bi] = true;
            idx[k] = bi;
            w[k] = s_arr[bi];  // weights gathered from sigmoid (pre-bias)
            wsum += w[k];
        }
        float inv = 1.f / (wsum + 1e-20f);
        for (int k = 0; k < TOPK; ++k) {
            topk_idx[t * TOPK + k] = idx[k];
            topk_w[t * TOPK + k] = w[k] * inv;
        }
    }
}

// ---------------- dispatch: count / scan / scatter ----------------
__global__ void count_kernel(const int* __restrict__ topk_idx, int* __restrict__ counts) {
    int a = blockIdx.x * blockDim.x + threadIdx.x;
    if (a < ASSIGN) atomicAdd(&counts[topk_idx[a]], 1);
}

__global__ void scan_kernel(const int* __restrict__ counts, int* __restrict__ starts,
                            int* __restrict__ cursor) {
    if (threadIdx.x == 0) {
        int acc = 0;
        for (int e2 = 0; e2 < E_NUM; ++e2) { starts[e2] = acc; cursor[e2] = acc; acc += counts[e2]; }
        starts[E_NUM] = acc;
    }
}

__global__ void scatter_kernel(const int* __restrict__ topk_idx, const float* __restrict__ topk_w,
                               int* __restrict__ cursor, int* __restrict__ perm,
                               float* __restrict__ pw) {
    int a = blockIdx.x * blockDim.x + threadIdx.x;
    if (a < ASSIGN) {
        int e2 = topk_idx[a];
        int pos = atomicAdd(&cursor[e2], 1);
        perm[pos] = a >> 2;  // token id
        pw[pos] = topk_w[a];
    }
}

// ---------------- pass 1: act = silu(X@Wg^T) * (X@Wu^T), grouped by expert ----------------
__global__ __launch_bounds__(256) void pass1_kernel(
    const float* __restrict__ x,
    const float* __restrict__ gate_w,   // [E,I,H]
    const float* __restrict__ up_w,     // [E,I,H]
    const float* __restrict__ sh_gate,  // [I,H]
    const float* __restrict__ sh_up,    // [I,H]
    const int* __restrict__ starts,
    const int* __restrict__ perm,
    float* __restrict__ act)            // [(ASSIGN+T), I]
{
    const int TILES = T_TOK / TM;  // 64
    int seg = blockIdx.x / TILES;
    int tile = blockIdx.x % TILES;
    int nbase = blockIdx.y * TN;

    int row0, nrows, actbase;
    const float* wg;
    const float* wu;
    if (seg == E_NUM) {
        row0 = tile * TM; nrows = TM; actbase = ASSIGN + row0;
        wg = sh_gate; wu = sh_up;
    } else {
        int s0 = starts[seg], s1 = starts[seg + 1];
        row0 = s0 + tile * TM;
        if (row0 >= s1) return;
        nrows = min(TM, s1 - row0);
        actbase = row0;
        wg = gate_w + (size_t)seg * I_DIM * H_DIM;
        wu = up_w + (size_t)seg * I_DIM * H_DIM;
    }

    __shared__ float As[KC][TM];
    __shared__ float Bg[KC][TN];
    __shared__ float Bu[KC][TN];

    int tid = threadIdx.x;
    int r = tid >> 2;          // 0..63 (staging row)
    int k4 = (tid & 3) * 4;    // 0,4,8,12
    int tm = tid & 15, tn = tid >> 4;

    int token;
    if (seg == E_NUM) token = row0 + r;
    else token = perm[row0 + ((r < nrows) ? r : 0)];
    const float* arow = x + (size_t)token * H_DIM;
    const float* bgrow = wg + (size_t)(nbase + r) * H_DIM;
    const float* burow = wu + (size_t)(nbase + r) * H_DIM;

    float accg[4][4] = {{0.f}};
    float accu[4][4] = {{0.f}};

    for (int k0 = 0; k0 < H_DIM; k0 += KC) {
        float4 av = *(const float4*)(arow + k0 + k4);
        float4 gv = *(const float4*)(bgrow + k0 + k4);
        float4 uv = *(const float4*)(burow + k0 + k4);
        As[k4 + 0][r] = av.x; As[k4 + 1][r] = av.y; As[k4 + 2][r] = av.z; As[k4 + 3][r] = av.w;
        Bg[k4 + 0][r] = gv.x; Bg[k4 + 1][r] = gv.y; Bg[k4 + 2][r] = gv.z; Bg[k4 + 3][r] = gv.w;
        Bu[k4 + 0][r] = uv.x; Bu[k4 + 1][r] = uv.y; Bu[k4 + 2][r] = uv.z; Bu[k4 + 3][r] = uv.w;
        __syncthreads();
#pragma unroll
        for (int k = 0; k < KC; ++k) {
            float4 a = *(const float4*)&As[k][tm * 4];
            float4 bg = *(const float4*)&Bg[k][tn * 4];
            float4 bu = *(const float4*)&Bu[k][tn * 4];
            float aa[4] = {a.x, a.y, a.z, a.w};
            float bga[4] = {bg.x, bg.y, bg.z, bg.w};
            float bua[4] = {bu.x, bu.y, bu.z, bu.w};
#pragma unroll
            for (int i2 = 0; i2 < 4; ++i2)
#pragma unroll
                for (int j = 0; j < 4; ++j) {
                    accg[i2][j] += aa[i2] * bga[j];
                    accu[i2][j] += aa[i2] * bua[j];
                }
        }
        __syncthreads();
    }

#pragma unroll
    for (int i2 = 0; i2 < 4; ++i2) {
        int rr = tm * 4 + i2;
        if (rr < nrows) {
            float res[4];
#pragma unroll
            for (int j = 0; j < 4; ++j) {
                float g = accg[i2][j], u = accu[i2][j];
                res[j] = (g / (1.f + expf(-g))) * u;  // silu(g)*u
            }
            float* op = &act[(size_t)(actbase + rr) * I_DIM + nbase + tn * 4];
            *(float4*)op = make_float4(res[0], res[1], res[2], res[3]);
        }
    }
}

// ---------------- pass 2: out[token] += w * (act @ Wd^T) ----------------
__global__ __launch_bounds__(256) void pass2_kernel(
    const float* __restrict__ act,
    const float* __restrict__ down_w,   // [E,H,I]
    const float* __restrict__ sh_down,  // [H,I]
    const int* __restrict__ starts,
    const int* __restrict__ perm,
    const float* __restrict__ pw,
    float* __restrict__ out)
{
    const int TILES = T_TOK / TM;
    int seg = blockIdx.x / TILES;
    int tile = blockIdx.x % TILES;
    int nbase = blockIdx.y * TN;  // over H

    int row0, nrows, actbase;
    const float* wd;
    if (seg == E_NUM) {
        row0 = tile * TM; nrows = TM; actbase = ASSIGN + row0;
        wd = sh_down;
    } else {
        int s0 = starts[seg], s1 = starts[seg + 1];
        row0 = s0 + tile * TM;
        if (row0 >= s1) return;
        nrows = min(TM, s1 - row0);
        actbase = row0;
        wd = down_w + (size_t)seg * H_DIM * I_DIM;
    }

    __shared__ float As[KC][TM];
    __shared__ float Bs[KC][TN];

    int tid = threadIdx.x;
    int r = tid >> 2;
    int k4 = (tid & 3) * 4;
    int tm = tid & 15, tn = tid >> 4;

    const float* arow = act + (size_t)(actbase + r) * I_DIM;
    const float* brow = wd + (size_t)(nbase + r) * I_DIM;

    float acc[4][4] = {{0.f}};

    for (int k0 = 0; k0 < I_DIM; k0 += KC) {
        float4 av = *(const float4*)(arow + k0 + k4);
        float4 bv = *(const float4*)(brow + k0 + k4);
        As[k4 + 0][r] = av.x; As[k4 + 1][r] = av.y; As[k4 + 2][r] = av.z; As[k4 + 3][r] = av.w;
        Bs[k4 + 0][r] = bv.x; Bs[k4 + 1][r] = bv.y; Bs[k4 + 2][r] = bv.z; Bs[k4 + 3][r] = bv.w;
        __syncthreads();
#pragma unroll
        for (int k = 0; k < KC; ++k) {
            float4 a = *(const float4*)&As[k][tm * 4];
            float4 b = *(const float4*)&Bs[k][tn * 4];
            float aa[4] = {a.x, a.y, a.z, a.w};
            float bb[4] = {b.x, b.y, b.z, b.w};
#pragma unroll
            for (int i2 = 0; i2 < 4; ++i2)
#pragma unroll
                for (int j = 0; j < 4; ++j) acc[i2][j] += aa[i2] * bb[j];
        }
        __syncthreads();
    }

#pragma unroll
    for (int i2 = 0; i2 < 4; ++i2) {
        int rr = tm * 4 + i2;
        if (rr < nrows) {
            int token; float w;
            if (seg == E_NUM) { token = tile * TM + rr; w = 1.f; }
            else { token = perm[row0 + rr]; w = pw[row0 + rr]; }
            float* op = &out[(size_t)token * H_DIM + nbase + tn * 4];
#pragma unroll
            for (int j = 0; j < 4; ++j) atomicAdd(&op[j], w * acc[i2][j]);
        }
    }
}

extern "C" void kernel_launch(void* const* d_in, const int* in_sizes, int n_in,
                              void* d_out, int out_size, void* d_ws, size_t ws_size,
                              hipStream_t stream) {
    (void)in_sizes; (void)n_in; (void)out_size; (void)ws_size;
    const float* x       = (const float*)d_in[0];
    const float* rw      = (const float*)d_in[1];
    const float* bias    = (const float*)d_in[2];
    const float* gate_w  = (const float*)d_in[3];
    const float* up_w    = (const float*)d_in[4];
    const float* down_w  = (const float*)d_in[5];
    const float* sh_gate = (const float*)d_in[6];
    const float* sh_up   = (const float*)d_in[7];
    const float* sh_down = (const float*)d_in[8];
    float* out = (float*)d_out;

    char* ws = (char*)d_ws;
    int*   topk_idx = (int*)(ws + 0);        // 16384 ints
    float* topk_w   = (float*)(ws + 65536);  // 16384 floats
    int*   counts   = (int*)(ws + 131072);   // 32
    int*   starts   = (int*)(ws + 131328);   // 33
    int*   cursor   = (int*)(ws + 131584);   // 32
    int*   perm     = (int*)(ws + 131840);   // 16384
    float* pw       = (float*)(ws + 197376); // 16384
    float* act      = (float*)(ws + 262912); // 20480*768 floats = 62.9 MB

    zero_kernel<<<4096, 256, 0, stream>>>(out, T_TOK * H_DIM / 4, counts);
    router_kernel<<<T_TOK, 128, 0, stream>>>(x, rw, bias, topk_idx, topk_w);
    count_kernel<<<ASSIGN / 256, 256, 0, stream>>>(topk_idx, counts);
    scan_kernel<<<1, 32, 0, stream>>>(counts, starts, cursor);
    scatter_kernel<<<ASSIGN / 256, 256, 0, stream>>>(topk_idx, topk_w, cursor, perm, pw);

    dim3 g1((E_NUM + 1) * (T_TOK / TM), I_DIM / TN);
    pass1_kernel<<<g1, 256, 0, stream>>>(x, gate_w, up_w, sh_gate, sh_up, starts, perm, act);
    dim3 g2((E_NUM + 1) * (T_TOK / TM), H_DIM / TN);
    pass2_kernel<<<g2, 256, 0, stream>>>(act, down_w, sh_down, starts, perm, pw, out);
}

// Round 9
// 773.173 us; speedup vs baseline: 4.6051x; 4.6051x over previous
//
#include <hip/hip_runtime.h>
#include <math.h>

#define T_TOK 4096
#define H_DIM 1024
#define I_DIM 768
#define E_NUM 32
#define G_NUM 8
#define TOPKG 4
#define TOPK 4
#define ASSIGN (T_TOK * TOPK) /* 16384 */

#define BM 128
#define BN 128
#define BK 64

typedef __attribute__((ext_vector_type(8))) short s16x8;
typedef __attribute__((ext_vector_type(4))) float f32x4;

__device__ __forceinline__ ushort f2bf(float f) {
    uint u = __builtin_bit_cast(uint, f);
    u += 0x7FFFu + ((u >> 16) & 1u);   // round-to-nearest-even
    return (ushort)(u >> 16);
}

// swizzled element offset into a [rows][64] bf16 LDS tile; chunk c in 16B units
__device__ __forceinline__ int swzo(int r, int c) {
    return r * 64 + ((c ^ (r & 7)) << 3);
}

__device__ __forceinline__ void cvt_store(ushort* dst, float4 u0, float4 u1) {
    s16x8 v;
    v[0] = (short)f2bf(u0.x); v[1] = (short)f2bf(u0.y);
    v[2] = (short)f2bf(u0.z); v[3] = (short)f2bf(u0.w);
    v[4] = (short)f2bf(u1.x); v[5] = (short)f2bf(u1.y);
    v[6] = (short)f2bf(u1.z); v[7] = (short)f2bf(u1.w);
    *(s16x8*)dst = v;
}

// ---------------- zero counts ----------------
__global__ void zcounts_kernel(int* __restrict__ counts) {
    if (threadIdx.x < E_NUM) counts[threadIdx.x] = 0;
}

// ---------------- router: fp32, identical math to R1 (passed) ----------------
__global__ __launch_bounds__(128) void router_kernel(
    const float* __restrict__ x, const float* __restrict__ rw,
    const float* __restrict__ bias, int* __restrict__ topk_idx,
    float* __restrict__ topk_w)
{
    int t = blockIdx.x;
    int tid = threadIdx.x;
    __shared__ float part[128];
    __shared__ float s_arr[E_NUM];
    __shared__ float sc_arr[E_NUM];

    int e = tid >> 2, sub = tid & 3;
    const float* xr = x + (size_t)t * H_DIM;
    const float* wr = rw + (size_t)e * H_DIM;
    float acc = 0.f;
    for (int h = sub * 4; h < H_DIM; h += 16) {
        float4 xv = *(const float4*)(xr + h);
        float4 wv = *(const float4*)(wr + h);
        acc += xv.x * wv.x + xv.y * wv.y + xv.z * wv.z + xv.w * wv.w;
    }
    part[tid] = acc;
    __syncthreads();
    if (tid < E_NUM) {
        float l = part[tid * 4 + 0] + part[tid * 4 + 1] + part[tid * 4 + 2] + part[tid * 4 + 3];
        float s = 1.f / (1.f + expf(-l));
        s_arr[tid] = s;
        sc_arr[tid] = s + bias[tid];
    }
    __syncthreads();
    if (tid == 0) {
        float gs[G_NUM];
        for (int g = 0; g < G_NUM; ++g) {
            float m1 = -1e30f, m2 = -1e30f;
            for (int j = 0; j < 4; ++j) {
                float v = sc_arr[g * 4 + j];
                if (v > m1) { m2 = m1; m1 = v; }
                else if (v > m2) { m2 = v; }
            }
            gs[g] = m1 + m2;
        }
        bool gsel[G_NUM];
        for (int g = 0; g < G_NUM; ++g) gsel[g] = false;
        for (int it = 0; it < TOPKG; ++it) {
            float best = -1e30f; int bi = 0;
            for (int g = 0; g < G_NUM; ++g)
                if (!gsel[g] && gs[g] > best) { best = gs[g]; bi = g; }
            gsel[bi] = true;
        }
        float sfc[E_NUM];
        for (int i2 = 0; i2 < E_NUM; ++i2) sfc[i2] = gsel[i2 >> 2] ? sc_arr[i2] : 0.0f;
        bool taken[E_NUM];
        for (int i2 = 0; i2 < E_NUM; ++i2) taken[i2] = false;
        int idx[TOPK]; float w[TOPK]; float wsum = 0.f;
        for (int k = 0; k < TOPK; ++k) {
            float best = -1e30f; int bi = 0;
            for (int i2 = 0; i2 < E_NUM; ++i2)
                if (!taken[i2] && sfc[i2] > best) { best = sfc[i2]; bi = i2; }
            taken[bi] = true;
            idx[k] = bi;
            w[k] = s_arr[bi];
            wsum += w[k];
        }
        float inv = 1.f / (wsum + 1e-20f);
        for (int k = 0; k < TOPK; ++k) {
            topk_idx[t * TOPK + k] = idx[k];
            topk_w[t * TOPK + k] = w[k] * inv;
        }
    }
}

// ---------------- dispatch: count / scan+worklist / scatter ----------------
__global__ void count_kernel(const int* __restrict__ topk_idx, int* __restrict__ counts) {
    int a = blockIdx.x * blockDim.x + threadIdx.x;
    if (a < ASSIGN) atomicAdd(&counts[topk_idx[a]], 1);
}

__global__ void scan_kernel(const int* __restrict__ counts, int* __restrict__ starts,
                            int* __restrict__ cursor, int* __restrict__ wl_seg,
                            int* __restrict__ wl_row0, int* __restrict__ wl_n) {
    if (threadIdx.x == 0) {
        int acc = 0;
        for (int e = 0; e < E_NUM; ++e) { starts[e] = acc; cursor[e] = acc; acc += counts[e]; }
        starts[E_NUM] = acc;
        int nt = 0;
        // routed tiles first (expert-major => consecutive tiles share expert weights)
        for (int e = 0; e < E_NUM; ++e)
            for (int r = starts[e]; r < starts[e + 1]; r += BM) {
                wl_seg[nt] = e; wl_row0[nt] = r; ++nt;
            }
        wl_n[1] = nt;   // routed tile count
        for (int r = 0; r < T_TOK; r += BM) {
            wl_seg[nt] = E_NUM; wl_row0[nt] = r; ++nt;
        }
        wl_n[0] = nt;   // total
    }
}

__global__ void scatter_kernel(const int* __restrict__ topk_idx, const float* __restrict__ topk_w,
                               int* __restrict__ cursor, int* __restrict__ perm,
                               float* __restrict__ pw) {
    int a = blockIdx.x * blockDim.x + threadIdx.x;
    if (a < ASSIGN) {
        int e2 = topk_idx[a];
        int pos = atomicAdd(&cursor[e2], 1);
        perm[pos] = a >> 2;
        pw[pos] = topk_w[a];
    }
}

// ---------------- pass 1: act = silu(X@Wg^T) * (X@Wu^T), bf16 MFMA ----------------
__global__ __launch_bounds__(256, 2) void pass1_kernel(
    const float* __restrict__ x,
    const float* __restrict__ gate_w, const float* __restrict__ up_w,
    const float* __restrict__ sh_gate, const float* __restrict__ sh_up,
    const int* __restrict__ starts, const int* __restrict__ perm,
    const int* __restrict__ wl_seg, const int* __restrict__ wl_row0,
    const int* __restrict__ wl_n,
    ushort* __restrict__ act)
{
    __shared__ __align__(16) ushort As[BM * BK];
    __shared__ __align__(16) ushort Bgs[BN * BK];
    __shared__ __align__(16) ushort Bus[BN * BK];

    const int NI = I_DIM / BN;                     // 6
    int NT = wl_n[0];
    int nwork = NT * NI;
    int Wper = (nwork + 7) >> 3;
    int slot = blockIdx.x >> 3;
    int w = (blockIdx.x & 7) * Wper + slot;        // XCD-chunked, tile-major
    if (slot >= Wper || w >= nwork) return;

    int tix = w / NI, nidx = w % NI;               // consecutive w share tile/expert
    int seg = wl_seg[tix];
    int row0 = wl_row0[tix];
    int nbase = nidx * BN;
    int nrows, actbase;
    const float* wg; const float* wu;
    if (seg == E_NUM) {
        nrows = BM; actbase = ASSIGN + row0;
        wg = sh_gate; wu = sh_up;
    } else {
        nrows = min(BM, starts[seg + 1] - row0);
        actbase = row0;
        wg = gate_w + (size_t)seg * (I_DIM * H_DIM);
        wu = up_w + (size_t)seg * (I_DIM * H_DIM);
    }

    int t = threadIdx.x;
    // staging: 4 consecutive lanes cover 64B of one row (coalesced)
    int sr = t >> 2;        // 0..63, rows {sr, sr+64}
    int scb = t & 3;        // chunks {scb, scb+4} (16B units)
    const float* pa[2]; const float* pg[2]; const float* pu[2];
#pragma unroll
    for (int i = 0; i < 2; ++i) {
        int r = sr + i * 64;
        int tok;
        if (seg == E_NUM) tok = row0 + r;
        else tok = perm[row0 + ((r < nrows) ? r : 0)];
        pa[i] = x + (size_t)tok * H_DIM;
        pg[i] = wg + (size_t)(nbase + r) * H_DIM;
        pu[i] = wu + (size_t)(nbase + r) * H_DIM;
    }
    int wo[2][2];
#pragma unroll
    for (int i = 0; i < 2; ++i)
#pragma unroll
        for (int ci = 0; ci < 2; ++ci) wo[i][ci] = swzo(sr + i * 64, scb + ci * 4);

    int l = t & 63;
    int wv = t >> 6, wr = wv >> 1, wc = wv & 1;
    int lr = l & 15, lg = l >> 4;
    int arow = wr * 64 + lr;
    int brow = wc * 64 + lr;

    f32x4 accg[4][4], accu[4][4];
#pragma unroll
    for (int mi = 0; mi < 4; ++mi)
#pragma unroll
        for (int ni = 0; ni < 4; ++ni) {
            accg[mi][ni] = (f32x4){0.f, 0.f, 0.f, 0.f};
            accu[mi][ni] = (f32x4){0.f, 0.f, 0.f, 0.f};
        }

    for (int k0 = 0; k0 < H_DIM; k0 += BK) {
#pragma unroll
        for (int i = 0; i < 2; ++i)
#pragma unroll
            for (int ci = 0; ci < 2; ++ci) {
                int c8 = (scb + ci * 4) * 8;
                const float4* sa = (const float4*)(pa[i] + k0 + c8);
                const float4* sg = (const float4*)(pg[i] + k0 + c8);
                const float4* su = (const float4*)(pu[i] + k0 + c8);
                cvt_store(&As[wo[i][ci]], sa[0], sa[1]);
                cvt_store(&Bgs[wo[i][ci]], sg[0], sg[1]);
                cvt_store(&Bus[wo[i][ci]], su[0], su[1]);
            }
        __syncthreads();
#pragma unroll
        for (int kk = 0; kk < 2; ++kk) {
            int cx = kk * 4 + lg;
            s16x8 af[4], bg[4], bu[4];
#pragma unroll
            for (int mi = 0; mi < 4; ++mi) {
                int r = arow + mi * 16;
                af[mi] = *(const s16x8*)(&As[r * 64 + ((cx ^ (r & 7)) << 3)]);
            }
#pragma unroll
            for (int ni = 0; ni < 4; ++ni) {
                int r = brow + ni * 16;
                int o = r * 64 + ((cx ^ (r & 7)) << 3);
                bg[ni] = *(const s16x8*)(&Bgs[o]);
                bu[ni] = *(const s16x8*)(&Bus[o]);
            }
#pragma unroll
            for (int mi = 0; mi < 4; ++mi)
#pragma unroll
                for (int ni = 0; ni < 4; ++ni) {
                    accg[mi][ni] = __builtin_amdgcn_mfma_f32_16x16x32_bf16(af[mi], bg[ni], accg[mi][ni], 0, 0, 0);
                    accu[mi][ni] = __builtin_amdgcn_mfma_f32_16x16x32_bf16(af[mi], bu[ni], accu[mi][ni], 0, 0, 0);
                }
        }
        __syncthreads();
    }

#pragma unroll
    for (int mi = 0; mi < 4; ++mi) {
        int rb = wr * 64 + mi * 16 + lg * 4;
#pragma unroll
        for (int q = 0; q < 4; ++q) {
            int r = rb + q;
            if (r < nrows) {
                ushort* orow = act + (size_t)(actbase + r) * I_DIM + nbase + wc * 64 + lr;
#pragma unroll
                for (int ni = 0; ni < 4; ++ni) {
                    float g = accg[mi][ni][q];
                    float u = accu[mi][ni][q];
                    float a = (g / (1.f + __expf(-g))) * u;   // silu(g)*u
                    orow[ni * 16] = f2bf(a);
                }
            }
        }
    }
}

// ---------------- pass 2: out = act @ Wd^T ----------------
// mode 0: shared expert — plain fp32 store, covers every out element (runs first)
// mode 1: routed — atomicAdd(w * acc) on top
__global__ __launch_bounds__(256, 2) void pass2_kernel(
    const ushort* __restrict__ act,
    const float* __restrict__ down_w, const float* __restrict__ sh_down,
    const int* __restrict__ starts, const int* __restrict__ perm,
    const int* __restrict__ wl_seg, const int* __restrict__ wl_row0,
    const int* __restrict__ wl_n, const float* __restrict__ pw,
    float* __restrict__ out, int mode)
{
    __shared__ __align__(16) ushort As[BM * BK];
    __shared__ __align__(16) ushort Bs[BN * BK];

    const int NH = H_DIM / BN;                     // 8
    int NT = (mode == 0) ? (T_TOK / BM) : wl_n[1];
    int nwork = NT * NH;
    int Wper = (nwork + 7) >> 3;
    int slot = blockIdx.x >> 3;
    int w = (blockIdx.x & 7) * Wper + slot;
    if (slot >= Wper || w >= nwork) return;

    int tix = w / NH, nidx = w % NH;
    int nbase = nidx * BN;
    int seg, row0, nrows, abase;
    const float* wd;
    if (mode == 0) {
        seg = E_NUM; row0 = tix * BM; nrows = BM; abase = ASSIGN + row0;
        wd = sh_down;
    } else {
        seg = wl_seg[tix];
        row0 = wl_row0[tix];
        nrows = min(BM, starts[seg + 1] - row0);
        abase = row0;
        wd = down_w + (size_t)seg * (H_DIM * I_DIM);
    }

    int t = threadIdx.x;
    int sr = t >> 2;
    int scb = t & 3;
    const ushort* pa[2]; const float* pb[2];
#pragma unroll
    for (int i = 0; i < 2; ++i) {
        int r = sr + i * 64;
        pa[i] = act + (size_t)(abase + ((r < nrows) ? r : 0)) * I_DIM;
        pb[i] = wd + (size_t)(nbase + r) * I_DIM;
    }
    int wo[2][2];
#pragma unroll
    for (int i = 0; i < 2; ++i)
#pragma unroll
        for (int ci = 0; ci < 2; ++ci) wo[i][ci] = swzo(sr + i * 64, scb + ci * 4);

    int l = t & 63;
    int wv = t >> 6, wr = wv >> 1, wc = wv & 1;
    int lr = l & 15, lg = l >> 4;
    int arow = wr * 64 + lr;
    int brow = wc * 64 + lr;

    f32x4 acc[4][4];
#pragma unroll
    for (int mi = 0; mi < 4; ++mi)
#pragma unroll
        for (int ni = 0; ni < 4; ++ni) acc[mi][ni] = (f32x4){0.f, 0.f, 0.f, 0.f};

    for (int k0 = 0; k0 < I_DIM; k0 += BK) {
#pragma unroll
        for (int i = 0; i < 2; ++i)
#pragma unroll
            for (int ci = 0; ci < 2; ++ci) {
                int c8 = (scb + ci * 4) * 8;
                uint4 va = *(const uint4*)(pa[i] + k0 + c8);   // bf16 pass-through
                const float4* sb = (const float4*)(pb[i] + k0 + c8);
                *(uint4*)(&As[wo[i][ci]]) = va;
                cvt_store(&Bs[wo[i][ci]], sb[0], sb[1]);
            }
        __syncthreads();
#pragma unroll
        for (int kk = 0; kk < 2; ++kk) {
            int cx = kk * 4 + lg;
            s16x8 af[4], bf[4];
#pragma unroll
            for (int mi = 0; mi < 4; ++mi) {
                int r = arow + mi * 16;
                af[mi] = *(const s16x8*)(&As[r * 64 + ((cx ^ (r & 7)) << 3)]);
            }
#pragma unroll
            for (int ni = 0; ni < 4; ++ni) {
                int r = brow + ni * 16;
                bf[ni] = *(const s16x8*)(&Bs[r * 64 + ((cx ^ (r & 7)) << 3)]);
            }
#pragma unroll
            for (int mi = 0; mi < 4; ++mi)
#pragma unroll
                for (int ni = 0; ni < 4; ++ni)
                    acc[mi][ni] = __builtin_amdgcn_mfma_f32_16x16x32_bf16(af[mi], bf[ni], acc[mi][ni], 0, 0, 0);
        }
        __syncthreads();
    }

#pragma unroll
    for (int mi = 0; mi < 4; ++mi) {
        int rb = wr * 64 + mi * 16 + lg * 4;
#pragma unroll
        for (int q = 0; q < 4; ++q) {
            int r = rb + q;
            if (r < nrows) {
                if (mode == 0) {
                    int token = row0 + r;
                    float* op = &out[(size_t)token * H_DIM + nbase + wc * 64 + lr];
#pragma unroll
                    for (int ni = 0; ni < 4; ++ni) op[ni * 16] = acc[mi][ni][q];
                } else {
                    int token = perm[row0 + r];
                    float wgt = pw[row0 + r];
                    float* op = &out[(size_t)token * H_DIM + nbase + wc * 64 + lr];
#pragma unroll
                    for (int ni = 0; ni < 4; ++ni) atomicAdd(&op[ni * 16], wgt * acc[mi][ni][q]);
                }
            }
        }
    }
}

extern "C" void kernel_launch(void* const* d_in, const int* in_sizes, int n_in,
                              void* d_out, int out_size, void* d_ws, size_t ws_size,
                              hipStream_t stream) {
    (void)in_sizes; (void)n_in; (void)out_size; (void)ws_size;
    const float* x       = (const float*)d_in[0];
    const float* rw      = (const float*)d_in[1];
    const float* bias    = (const float*)d_in[2];
    const float* gate_w  = (const float*)d_in[3];
    const float* up_w    = (const float*)d_in[4];
    const float* down_w  = (const float*)d_in[5];
    const float* sh_gate = (const float*)d_in[6];
    const float* sh_up   = (const float*)d_in[7];
    const float* sh_down = (const float*)d_in[8];
    float* out = (float*)d_out;

    char* ws = (char*)d_ws;
    int*    topk_idx = (int*)(ws + 0);         // 64 KB
    float*  topk_w   = (float*)(ws + 65536);   // 64 KB
    int*    counts   = (int*)(ws + 131072);    // 128 B
    int*    starts   = (int*)(ws + 131200);    // 33 ints
    int*    cursor   = (int*)(ws + 131456);    // 32 ints
    int*    wl_seg   = (int*)(ws + 131584);    // <=256 entries
    int*    wl_row0  = (int*)(ws + 132608);
    int*    wl_n     = (int*)(ws + 133632);    // [0]=total, [1]=routed
    int*    perm     = (int*)(ws + 135168);    // 64 KB
    float*  pw       = (float*)(ws + 200704);  // 64 KB
    ushort* act      = (ushort*)(ws + 266240); // 20480*768*2 = 30 MB (ends ~31.7 MB)

    zcounts_kernel<<<1, 64, 0, stream>>>(counts);
    router_kernel<<<T_TOK, 128, 0, stream>>>(x, rw, bias, topk_idx, topk_w);
    count_kernel<<<ASSIGN / 256, 256, 0, stream>>>(topk_idx, counts);
    scan_kernel<<<1, 32, 0, stream>>>(counts, starts, cursor, wl_seg, wl_row0, wl_n);
    scatter_kernel<<<ASSIGN / 256, 256, 0, stream>>>(topk_idx, topk_w, cursor, perm, pw);

    pass1_kernel<<<2048, 256, 0, stream>>>(x, gate_w, up_w, sh_gate, sh_up,
                                           starts, perm, wl_seg, wl_row0, wl_n, act);
    // shared first (plain stores initialize every out element), then routed atomics
    pass2_kernel<<<256, 256, 0, stream>>>(act, down_w, sh_down, starts, perm,
                                          wl_seg, wl_row0, wl_n, pw, out, 0);
    pass2_kernel<<<2048, 256, 0, stream>>>(act, down_w, sh_down, starts, perm,
                                           wl_seg, wl_row0, wl_n, pw, out, 1);
}